// Round 8
// baseline (200.861 us; speedup 1.0000x reference)
//
#include <hip/hip_runtime.h>

// AttnBlock: GN(32) -> 1x1 qkv -> full attention (B=2,C=512,N=4096) -> 1x1 proj -> +x
// R8: conflict-free fp8 LDS. All fp8 operand buffers store the k-dim PERMUTED within
// each 128-byte block (swap bit-fields 3-4 <-> 5-6: fragments in [kch][kk] order), so
// GEMM fragment reads become ds_read_b128 (2 MFMA k-steps per read, uniform bank load,
// 0 conflicts - the R7 b64 path had a structural 4-way alias = 4.2M conflict cycles).
// Producers (gn_apply8/wconv8/qkv epi/U8 epi/transpose_v8/merge) write via perm index.
// Also: exp2f with log2(e) folded into alpha (saves a VALU mul on 32M elements).

typedef unsigned short u16;
typedef unsigned int u32;
typedef unsigned char u8;
typedef float f32x4 __attribute__((ext_vector_type(4)));
typedef long l2 __attribute__((ext_vector_type(2)));

#define NPOS 4096
#define CCH 512

// permute k-index within its 128-byte block: swap bits 3-4 with bits 5-6 (self-inverse)
__device__ __forceinline__ int kperm(int k) {
  return (k & ~0x78) | ((k >> 2) & 0x18) | ((k << 2) & 0x60);
}

__device__ __forceinline__ u16 f2bf(float f) {
  u32 u = __builtin_bit_cast(u32, f);
  u += 0x7fffu + ((u >> 16) & 1u);
  return (u16)(u >> 16);
}
__device__ __forceinline__ float bf2f(u16 h) {
  u32 u = ((u32)h) << 16;
  return __builtin_bit_cast(float, u);
}
__device__ __forceinline__ u8 f2fp8(float f) {
  u32 pk = __builtin_amdgcn_cvt_pk_fp8_f32(f, f, 0, false);
  return (u8)(pk & 0xff);
}

__device__ __forceinline__ void load16_lds8(const u8* g, u8* l) {
  __builtin_amdgcn_global_load_lds(
      (const __attribute__((address_space(1))) void*)g,
      (__attribute__((address_space(3))) void*)l, 16, 0, 0);
}

// ---------------- GroupNorm partial stats ----------------
__global__ __launch_bounds__(256) void gn_stats_part(const float* __restrict__ x,
                                                     float2* __restrict__ part) {
  int id = blockIdx.x;
  const float4* p = (const float4*)(x + (size_t)id * 16384);
  float s = 0.f, s2 = 0.f;
  for (int i = threadIdx.x; i < 4096; i += 256) {
    float4 u = p[i];
    s += u.x + u.y + u.z + u.w;
    s2 += u.x * u.x + u.y * u.y + u.z * u.z + u.w * u.w;
  }
  for (int o = 32; o; o >>= 1) {
    s += __shfl_xor(s, o);
    s2 += __shfl_xor(s2, o);
  }
  __shared__ float rs[4], rq[4];
  int lane = threadIdx.x & 63, w = threadIdx.x >> 6;
  if (lane == 0) { rs[w] = s; rq[w] = s2; }
  __syncthreads();
  if (threadIdx.x == 0)
    part[id] = make_float2(rs[0] + rs[1] + rs[2] + rs[3], rq[0] + rq[1] + rq[2] + rq[3]);
}

// normalize + transpose: x[b][c][n] (f32) -> h8[b][n][perm(c)] (fp8)
__global__ __launch_bounds__(256) void gn_apply8(const float* __restrict__ x,
                                                 const float* __restrict__ gnw,
                                                 const float* __restrict__ gnb,
                                                 const float2* __restrict__ pstats,
                                                 u8* __restrict__ h8) {
  int b = blockIdx.z, c0 = blockIdx.y * 64, n0 = blockIdx.x * 64;
  __shared__ u8 lt[64][80];
  const float* xb = x + (size_t)b * CCH * NPOS;
  int tid = threadIdx.x;
#pragma unroll
  for (int it = 0; it < 4; ++it) {
    int ci = (tid >> 4) + it * 16;
    int nj = (tid & 15) * 4;
    int c = c0 + ci;
    float4 v = *(const float4*)&xb[(size_t)c * NPOS + n0 + nj];
    const float2* pp = pstats + ((size_t)b * 32 + (c >> 4)) * 4;
    float s = pp[0].x + pp[1].x + pp[2].x + pp[3].x;
    float s2 = pp[0].y + pp[1].y + pp[2].y + pp[3].y;
    float mu = s * (1.f / 65536.f);
    float var = s2 * (1.f / 65536.f) - mu * mu;
    float rst = rsqrtf(var + 1e-6f);
    float w = gnw[c] * rst;
    float bb = gnb[c] - mu * w;
    lt[nj + 0][ci] = f2fp8(v.x * w + bb);
    lt[nj + 1][ci] = f2fp8(v.y * w + bb);
    lt[nj + 2][ci] = f2fp8(v.z * w + bb);
    lt[nj + 3][ci] = f2fp8(v.w * w + bb);
  }
  __syncthreads();
  int ni = tid >> 2, c16 = (tid & 3) * 16;
  uint4 o = *(const uint4*)&lt[ni][c16];
  u8* row = h8 + ((size_t)b * NPOS + n0 + ni) * CCH;
  int pc = kperm(c0 + c16);  // 8-byte halves are contiguous under perm
  *(uint2*)&row[pc] = make_uint2(o.x, o.y);
  *(uint2*)&row[kperm(c0 + c16 + 8)] = make_uint2(o.z, o.w);
}

// -------- weight f32 -> fp8 (k=cin permuted) + qkv bias pack --------
__global__ __launch_bounds__(256) void wconv8(const float* __restrict__ w0,
                                              const float* __restrict__ w1,
                                              const float* __restrict__ w2,
                                              const float* __restrict__ w3,
                                              u8* __restrict__ dst,
                                              const float* __restrict__ bq,
                                              const float* __restrict__ bk,
                                              const float* __restrict__ bv,
                                              float* __restrict__ bqkv) {
  int which = blockIdx.y;
  int bx = blockIdx.x;
  int t = threadIdx.x;
  if (bx == 256) {
    if (which < 3) {
      const float* bsrc = which == 0 ? bq : which == 1 ? bk : bv;
      bqkv[which * 512 + t] = bsrc[t];
      bqkv[which * 512 + 256 + t] = bsrc[256 + t];
    }
    return;
  }
  const float* src = which == 0 ? w0 : which == 1 ? w1 : which == 2 ? w2 : w3;
  u8* d = dst + (size_t)which * (CCH * CCH);
  int i = bx * 256 + t;  // dword i = bytes 4i..4i+3; row = (4i)>>9, c = (4i)&511
  float4 v = ((const float4*)src)[i];
  u32 pk = __builtin_amdgcn_cvt_pk_fp8_f32(v.x, v.y, 0, false);
  pk = __builtin_amdgcn_cvt_pk_fp8_f32(v.z, v.w, pk, true);
  int byte = i * 4;
  int c = byte & 511;
  ((u32*)d)[((byte & ~511) | kperm(c)) >> 2] = pk;
}

// ------- fp8 GEMM, BK=128, permuted-k operands, b128 fragment reads. -------
// EPI: 0 fp8(v+bias[n]) with q/k cols perm'd, 1 f32 alpha*v+bias[m]+resid,
//      2 U8=fp8(4*exp2(clamp(alpha*v))) at perm'd cols + lpart row-sums.
template <int EPI, bool SWIZ>
__global__ __launch_bounds__(256, 4) void gemm_f8(const u8* __restrict__ A,
                                                  const u8* __restrict__ Bm,
                                                  void* __restrict__ Cv,
                                                  const float* __restrict__ bias,
                                                  const float* __restrict__ resid,
                                                  float* __restrict__ lpart,
                                                  float alpha, int K,
                                                  int lda, int ldb, int ldc,
                                                  long sA, long sB, long sC, long sR) {
  const int b = blockIdx.z;
  int bx = blockIdx.x, by = blockIdx.y;
  if (SWIZ) {
    int id = by * gridDim.x + bx;
    int g = id >> 8;
    int w = id & 255;
    bx = (g << 3) | (w & 7);
    by = w >> 3;
  }
  A += (size_t)b * sA;
  Bm += (size_t)b * sB;
  const int m0 = by * 128, n0 = bx * 128;
  __shared__ u8 sAt[128 * 128];
  __shared__ u8 sBt[128 * 128];
  const int tid = threadIdx.x, wave = tid >> 6, lane = tid & 63;
  const int lrow = lane & 15, kch = lane >> 4;
  const int wm = (wave >> 1) * 64, wn = (wave & 1) * 64;
  const int srow = lane >> 3;
  const int sseg = ((lane & 7) ^ srow) * 16;
  f32x4 acc[4][4] = {};

  for (int k0 = 0; k0 < K; k0 += 128) {
#pragma unroll
    for (int r = 0; r < 4; ++r) {
      int ch = wave * 4 + r;
      load16_lds8(A + (size_t)(m0 + ch * 8 + srow) * lda + (k0 + sseg), sAt + ch * 1024);
      load16_lds8(Bm + (size_t)(n0 + ch * 8 + srow) * ldb + (k0 + sseg), sBt + ch * 1024);
    }
    __syncthreads();
#pragma unroll
    for (int kkhi = 0; kkhi < 2; ++kkhi) {
      const int slot = (kch << 1) | kkhi;
      l2 af[4], bf[4];
#pragma unroll
      for (int i = 0; i < 4; ++i) {
        int ra = wm + i * 16 + lrow;
        af[i] = *(const l2*)(sAt + ra * 128 + ((slot ^ (ra & 7)) << 4));
        int rb = wn + i * 16 + lrow;
        bf[i] = *(const l2*)(sBt + rb * 128 + ((slot ^ (rb & 7)) << 4));
      }
#pragma unroll
      for (int i = 0; i < 4; ++i)
#pragma unroll
        for (int j = 0; j < 4; ++j)
          acc[i][j] =
              __builtin_amdgcn_mfma_f32_16x16x32_fp8_fp8(af[i].x, bf[j].x, acc[i][j], 0, 0, 0);
#pragma unroll
      for (int i = 0; i < 4; ++i)
#pragma unroll
        for (int j = 0; j < 4; ++j)
          acc[i][j] =
              __builtin_amdgcn_mfma_f32_16x16x32_fp8_fp8(af[i].y, bf[j].y, acc[i][j], 0, 0, 0);
    }
    __syncthreads();
  }

  const int col = lane & 15, rbase = (lane >> 4) * 4;
  const size_t cb = (size_t)b * sC;
  float rsum[4][4];
  if (EPI == 2) {
#pragma unroll
    for (int i = 0; i < 4; ++i)
#pragma unroll
      for (int r = 0; r < 4; ++r) rsum[i][r] = 0.f;
  }
#pragma unroll
  for (int i = 0; i < 4; ++i) {
    int mrow = m0 + wm + i * 16 + rbase;
#pragma unroll
    for (int j = 0; j < 4; ++j) {
      int ncol = n0 + wn + j * 16 + col;
      float bcol = (EPI == 0) ? bias[ncol] : 0.f;
      // consumer k-dim is permuted for EPI 0 (q/k cols only) and EPI 2
      int scol = ncol;
      if (EPI == 0 && ncol < 1024) scol = kperm(ncol);
      if (EPI == 2) scol = kperm(ncol);
#pragma unroll
      for (int r = 0; r < 4; ++r) {
        int m = mrow + r;
        float v = acc[i][j][r];
        if (EPI == 0) {
          ((u8*)Cv)[cb + (size_t)m * ldc + scol] = f2fp8(v + bcol);
        } else if (EPI == 1) {
          v = v * alpha + bias[m] + resid[(size_t)b * sR + (size_t)m * ldc + ncol];
          ((float*)Cv)[cb + (size_t)m * ldc + ncol] = v;
        } else {
          float s = fminf(fmaxf(v * alpha, -14.f), 6.49f);  // alpha includes log2(e)
          float e = exp2f(s);
          rsum[i][r] += e;
          ((u8*)Cv)[cb + (size_t)m * ldc + scol] = f2fp8(4.f * e);
        }
      }
    }
  }
  if (EPI == 2) {
#pragma unroll
    for (int i = 0; i < 4; ++i) {
#pragma unroll
      for (int r = 0; r < 4; ++r) {
        float v = rsum[i][r];
        v += __shfl_xor(v, 1);
        v += __shfl_xor(v, 2);
        v += __shfl_xor(v, 4);
        v += __shfl_xor(v, 8);
        if ((lane & 15) == 0) {
          int m = m0 + wm + i * 16 + rbase + r;
          lpart[((size_t)b * NPOS + m) * 64 + bx * 2 + (wave & 1)] = v;
        }
      }
    }
  }
}

// ------- PV GEMM fp8 (permuted-k U8/V8, b128 reads): part = U8 . V8^T raw -------
__global__ __launch_bounds__(256, 4) void gemm_pv_fp8(const u8* __restrict__ Um,
                                                      const u8* __restrict__ Vm,
                                                      u16* __restrict__ part,
                                                      const float* __restrict__ lpart,
                                                      float* __restrict__ lsum) {
  const int b = blockIdx.z >> 2, slice = blockIdx.z & 3;
  const int id = blockIdx.x + (blockIdx.y << 2);
  const int xcd = id & 7, j = id >> 3;
  const int bx = j & 3, by = xcd + ((j >> 2) << 3);
  const u8* A = Um + (size_t)b * ((size_t)NPOS * NPOS) + (size_t)slice * 1024;
  const u8* Bv = Vm + (size_t)b * (CCH * NPOS) + (size_t)slice * 1024;
  const int m0 = by * 128, n0 = bx * 128;
  __shared__ u8 sA[128 * 128];
  __shared__ u8 sB[128 * 128];
  const int tid = threadIdx.x, wave = tid >> 6, lane = tid & 63;
  const int lrow = lane & 15, kch = lane >> 4;
  const int wm = (wave >> 1) * 64, wn = (wave & 1) * 64;
  const int srow = lane >> 3;
  const int sseg = ((lane & 7) ^ srow) * 16;
  f32x4 acc[4][4] = {};

  for (int k0 = 0; k0 < 1024; k0 += 128) {
#pragma unroll
    for (int r = 0; r < 4; ++r) {
      int ch = wave * 4 + r;
      load16_lds8(A + (size_t)(m0 + ch * 8 + srow) * NPOS + (k0 + sseg), sA + ch * 1024);
      load16_lds8(Bv + (size_t)(n0 + ch * 8 + srow) * NPOS + (k0 + sseg), sB + ch * 1024);
    }
    __syncthreads();
#pragma unroll
    for (int kkhi = 0; kkhi < 2; ++kkhi) {
      const int slot = (kch << 1) | kkhi;
      l2 af[4], bf[4];
#pragma unroll
      for (int i = 0; i < 4; ++i) {
        int ra = wm + i * 16 + lrow;
        af[i] = *(const l2*)(sA + ra * 128 + ((slot ^ (ra & 7)) << 4));
        int rb = wn + i * 16 + lrow;
        bf[i] = *(const l2*)(sB + rb * 128 + ((slot ^ (rb & 7)) << 4));
      }
#pragma unroll
      for (int i = 0; i < 4; ++i)
#pragma unroll
        for (int jj = 0; jj < 4; ++jj)
          acc[i][jj] =
              __builtin_amdgcn_mfma_f32_16x16x32_fp8_fp8(af[i].x, bf[jj].x, acc[i][jj], 0, 0, 0);
#pragma unroll
      for (int i = 0; i < 4; ++i)
#pragma unroll
        for (int jj = 0; jj < 4; ++jj)
          acc[i][jj] =
              __builtin_amdgcn_mfma_f32_16x16x32_fp8_fp8(af[i].y, bf[jj].y, acc[i][jj], 0, 0, 0);
    }
    __syncthreads();
  }

  const int col = lane & 15, rbase = (lane >> 4) * 4;
  u16* dst = part + (size_t)slice * ((size_t)2 * NPOS * CCH) + (size_t)b * (NPOS * CCH);
#pragma unroll
  for (int i = 0; i < 4; ++i) {
    int mrow = m0 + wm + i * 16 + rbase;
#pragma unroll
    for (int jj = 0; jj < 4; ++jj) {
      int ncol = n0 + wn + jj * 16 + col;
#pragma unroll
      for (int r = 0; r < 4; ++r)
        dst[(size_t)(mrow + r) * CCH + ncol] = f2bf(acc[i][jj][r]);
    }
  }
  if (bx == 0 && tid < 128) {
    const float* lp = lpart + ((size_t)b * NPOS + m0 + tid) * 64;
    float s = 0.f;
#pragma unroll
    for (int c = 0; c < 64; ++c) s += lp[c];
    lsum[(size_t)b * NPOS + m0 + tid] = s;
  }
}

// ------- merge 4 bf16 partials, /lsum -> o8[q][perm(c)] = fp8(32*o) ------
__global__ __launch_bounds__(256) void merge_pv8(const u16* __restrict__ part,
                                                 const float* __restrict__ lsum,
                                                 u8* __restrict__ dst) {
  const long sl = 4194304;
  int i = blockIdx.x * 256 + threadIdx.x;  // 8 elems (one q, 8 d) per thread
  long e0 = (long)i * 8;
  int q = (int)((e0 >> 9) & 4095);
  int b = (int)(e0 >> 21);
  int c8 = (int)(e0 & 511);
  float inv = 8.f / lsum[(size_t)b * NPOS + q];
  uint4 a = ((const uint4*)part)[i];
  uint4 bb = ((const uint4*)(part + sl))[i];
  uint4 c = ((const uint4*)(part + 2 * sl))[i];
  uint4 d = ((const uint4*)(part + 3 * sl))[i];
  u32 wa[4] = {a.x, a.y, a.z, a.w}, wb_[4] = {bb.x, bb.y, bb.z, bb.w};
  u32 wc[4] = {c.x, c.y, c.z, c.w}, wd[4] = {d.x, d.y, d.z, d.w};
  float v[8];
#pragma unroll
  for (int j = 0; j < 4; ++j) {
    v[2 * j] = (bf2f((u16)(wa[j] & 0xffff)) + bf2f((u16)(wb_[j] & 0xffff)) +
                bf2f((u16)(wc[j] & 0xffff)) + bf2f((u16)(wd[j] & 0xffff))) * inv;
    v[2 * j + 1] = (bf2f((u16)(wa[j] >> 16)) + bf2f((u16)(wb_[j] >> 16)) +
                    bf2f((u16)(wc[j] >> 16)) + bf2f((u16)(wd[j] >> 16))) * inv;
  }
  uint2 o;
  u32 p0 = __builtin_amdgcn_cvt_pk_fp8_f32(v[0], v[1], 0, false);
  p0 = __builtin_amdgcn_cvt_pk_fp8_f32(v[2], v[3], p0, true);
  u32 p1 = __builtin_amdgcn_cvt_pk_fp8_f32(v[4], v[5], 0, false);
  p1 = __builtin_amdgcn_cvt_pk_fp8_f32(v[6], v[7], p1, true);
  o.x = p0;
  o.y = p1;
  // dest row q, permuted 8-byte group
  *(uint2*)&dst[((size_t)b * NPOS + q) * CCH + kperm(c8)] = o;
}

// ------- transpose fp8: qkv8 v-cols (plain) -> v8[b][d][perm(n)] -------
__global__ __launch_bounds__(256) void transpose_v8(const u8* __restrict__ src,
                                                    u8* __restrict__ dst, int srcld) {
  int b = blockIdx.z, n0 = blockIdx.x * 64, d0 = blockIdx.y * 64;
  __shared__ u8 lt[64][80];
  const u8* s = src + (size_t)b * NPOS * srcld;
  u8* d = dst + (size_t)b * CCH * NPOS;
  int t = threadIdx.x;
  {
    int r = t >> 2, c16 = (t & 3) * 16;
    uint4 v = *(const uint4*)&s[(size_t)(n0 + r) * srcld + d0 + c16];
    *(uint4*)&lt[r][c16] = v;
  }
  __syncthreads();
  {
    int dr = t >> 2, c16 = (t & 3) * 16;
    u8 tmp[16];
#pragma unroll
    for (int j = 0; j < 16; ++j) tmp[j] = lt[c16 + j][dr];
    uint4 o = *(uint4*)tmp;
    u8* row = d + (size_t)(d0 + dr) * NPOS;
    *(uint2*)&row[kperm(n0 + c16)] = make_uint2(o.x, o.y);
    *(uint2*)&row[kperm(n0 + c16 + 8)] = make_uint2(o.z, o.w);
  }
}

extern "C" void kernel_launch(void* const* d_in, const int* in_sizes, int n_in,
                              void* d_out, int out_size, void* d_ws, size_t ws_size,
                              hipStream_t stream) {
  const float* x = (const float*)d_in[0];
  const float* gnw = (const float*)d_in[1];
  const float* gnb = (const float*)d_in[2];
  const float* wq = (const float*)d_in[3];
  const float* bq = (const float*)d_in[4];
  const float* wk = (const float*)d_in[5];
  const float* bk = (const float*)d_in[6];
  const float* wv = (const float*)d_in[7];
  const float* bv = (const float*)d_in[8];
  const float* wp = (const float*)d_in[9];
  const float* bp = (const float*)d_in[10];
  float* out = (float*)d_out;

  char* ws = (char*)d_ws;
  size_t off = 0;
  auto alloc = [&](size_t bytes) {
    void* p = ws + off;
    off += (bytes + 1023) & ~(size_t)1023;
    return p;
  };
  float2* pstats = (float2*)alloc(256 * sizeof(float2));
  u8* w8 = (u8*)alloc((size_t)4 * CCH * CCH);          // 1MB wq|wk|wv|wp fp8 (perm k)
  u8* wp8 = w8 + 3 * CCH * CCH;
  float* bqkv = (float*)alloc(1536 * sizeof(float));
  u8* h8 = (u8*)alloc((size_t)2 * NPOS * CCH);         // 4MB [b][n][perm c]
  u8* qkv8 = (u8*)alloc((size_t)2 * NPOS * 1536);      // 12MB [b][n][q|k perm, v plain]
  u8* v8 = (u8*)alloc((size_t)2 * CCH * NPOS);         // 4MB [b][d][perm n]
  u8* U8 = (u8*)alloc((size_t)2 * NPOS * NPOS);        // 32MB [b][q][perm nk] = 4*exp
  float* lpart = (float*)alloc((size_t)2 * NPOS * 64 * 4);  // 2MB
  float* lsum = (float*)alloc((size_t)2 * NPOS * 4);
  u16* part_pv = (u16*)alloc((size_t)4 * 2 * NPOS * CCH * 2);  // 32MB bf16 partials
  u8* o8 = (u8*)alloc((size_t)2 * NPOS * CCH);         // 4MB [b][n][perm c] = 32*o

  const long sHC8 = (long)NPOS * CCH;
  const long sQKV8 = (long)NPOS * 1536;
  const long sSS8 = (long)NPOS * NPOS;
  const long sOUT = (long)CCH * NPOS;
  const float scale2 = 0.044194173824159216f * 1.4426950408889634f;  // /sqrt(512)*log2(e)

  gn_stats_part<<<256, 256, 0, stream>>>(x, pstats);
  gn_apply8<<<dim3(64, 8, 2), 256, 0, stream>>>(x, gnw, gnb, pstats, h8);
  wconv8<<<dim3(257, 4), 256, 0, stream>>>(wq, wk, wv, wp, w8, bq, bk, bv, bqkv);
  // fused qkv: qkv8[b][n][0:1536] = fp8(h8 . (wq|wk|wv)^T + bias)
  gemm_f8<0, false><<<dim3(12, 32, 2), 256, 0, stream>>>(
      h8, w8, qkv8, bqkv, nullptr, nullptr, 1.f, CCH, CCH, CCH, 1536,
      sHC8, 0, sQKV8, 0);
  transpose_v8<<<dim3(64, 8, 2), 256, 0, stream>>>(qkv8 + 1024, v8, 1536);
  // U8 = fp8(4*exp2(clamp(scale2 * q.k^T))) + lpart row-sums; L2 panel swizzle
  gemm_f8<2, true><<<dim3(32, 32, 2), 256, 0, stream>>>(
      qkv8, qkv8 + 512, U8, nullptr, nullptr, lpart, scale2, CCH, 1536, 1536, NPOS,
      sQKV8, sQKV8, sSS8, 0);
  // PV split-K=4 into bf16 partials; bx==0 folds lpart->lsum
  gemm_pv_fp8<<<dim3(4, 32, 8), 256, 0, stream>>>(U8, v8, part_pv, lpart, lsum);
  merge_pv8<<<2048, 256, 0, stream>>>(part_pv, lsum, o8);
  // proj: out[b][d][n] = (wp . o8^T)/32 + bp + x
  gemm_f8<1, false><<<dim3(32, 4, 2), 256, 0, stream>>>(
      wp8, o8, out, bp, x, nullptr, 1.f / 32.f, CCH, CCH, CCH, NPOS,
      0, sHC8, sOUT, sOUT);
}